// Round 1
// baseline (284.439 us; speedup 1.0000x reference)
//
#include <hip/hip_runtime.h>
#include <math.h>

// Problem constants
#define BATCH 8
#define NN 64
#define DD 65536          // 64*32*32 feature length (contiguous per [b,n])
#define CH 64             // K-chunks per batch -> grid = 8*64 = 512 blocks
#define KC (DD / CH)      // 1024 K per block
#define BK 64             // K per LDS tile
#define NIT (KC / BK)     // 16 tile iterations per block
#define LSTRIDE 72        // LDS row stride in halfwords (64 + 8 pad: breaks bank aliasing)

typedef float  floatx4 __attribute__((ext_vector_type(4)));
typedef __bf16 bf16x8  __attribute__((ext_vector_type(8)));

// fp32 -> bf16 round-to-nearest-even (bit trick; inputs are finite randoms)
static __device__ __forceinline__ unsigned short f2bf(float f) {
    union { float f; unsigned u; } x;
    x.f = f;
    unsigned r = x.u + 0x7FFFu + ((x.u >> 16) & 1u);
    return (unsigned short)(r >> 16);
}

// ---------------------------------------------------------------------------
// Stage 1: partial Gram matrices G[b] = F F^T accumulated via atomics.
// Block = (b, chunk c). 256 threads = 4 waves. Each wave owns one 16-row band
// of the 64x64 output and computes 4 16x16 tiles (all 4 col-bands).
// A-frag and B-frag of a Gram matrix have identical lane layouts, so both
// operands come from the same LDS fragment reads.
// ---------------------------------------------------------------------------
__global__ __launch_bounds__(256) void gram_kernel(const float* __restrict__ a,
                                                   float* __restrict__ gram) {
    __shared__ __align__(16) unsigned short lds[NN * LSTRIDE];

    const int bid = blockIdx.x;
    const int b = bid >> 6;          // / CH
    const int c = bid & (CH - 1);
    const float* base = a + (size_t)b * NN * DD + (size_t)c * KC;

    const int tid  = threadIdx.x;
    const int w    = tid >> 6;       // wave id 0..3 -> output row band
    const int lane = tid & 63;
    const int m    = lane & 15;
    const int q    = lane >> 4;

    floatx4 acc[4];
    for (int t = 0; t < 4; ++t) acc[t] = (floatx4)0.0f;

    // Coalesced load mapping: flat float4 index F = sub*256 + tid,
    // row = F>>4 (64 rows), kq = F&15 (16 float4 per 64-wide K tile).
    float4 regs[4];
    for (int sub = 0; sub < 4; ++sub) {
        int F = sub * 256 + tid;
        int row = F >> 4, kq = F & 15;
        regs[sub] = *(const float4*)(base + (size_t)row * DD + kq * 4);
    }

    for (int kt = 0; kt < NIT; ++kt) {
        // stage current regs into LDS as bf16
        for (int sub = 0; sub < 4; ++sub) {
            int F = sub * 256 + tid;
            int row = F >> 4, kq = F & 15;
            ushort4 h;
            h.x = f2bf(regs[sub].x);
            h.y = f2bf(regs[sub].y);
            h.z = f2bf(regs[sub].z);
            h.w = f2bf(regs[sub].w);
            *reinterpret_cast<ushort4*>(&lds[row * LSTRIDE + kq * 4]) = h;
        }
        __syncthreads();

        // prefetch next tile into regs (overlaps with MFMA phase below)
        if (kt + 1 < NIT) {
            const float* nb = base + (size_t)(kt + 1) * BK;
            for (int sub = 0; sub < 4; ++sub) {
                int F = sub * 256 + tid;
                int row = F >> 4, kq = F & 15;
                regs[sub] = *(const float4*)(nb + (size_t)row * DD + kq * 4);
            }
        }

        // MFMA over this BK=64 tile: two K=32 steps
        for (int s = 0; s < 2; ++s) {
            int kb = s * 32 + q * 8;
            bf16x8 fr[4];
            for (int t = 0; t < 4; ++t)
                fr[t] = *reinterpret_cast<const bf16x8*>(&lds[(16 * t + m) * LSTRIDE + kb]);
            bf16x8 A = fr[w];
            for (int t = 0; t < 4; ++t)
                acc[t] = __builtin_amdgcn_mfma_f32_16x16x32_bf16(A, fr[t], acc[t], 0, 0, 0);
        }
        __syncthreads();
    }

    // C/D layout: C[row=(lane>>4)*4+r][col=lane&15] (swap-safe: G symmetric)
    float* g = gram + b * (NN * NN);
    for (int t = 0; t < 4; ++t)
        for (int r = 0; r < 4; ++r) {
            int i = 16 * w + q * 4 + r;
            int j = 16 * t + m;
            atomicAdd(&g[i * NN + j], acc[t][r]);
        }
}

// ---------------------------------------------------------------------------
// Stage 2: per-batch CRF iterations. 8 blocks x 256 threads.
// thread = (i = tid&63, jq = tid>>6): each thread owns a 16-wide j-chunk of row i.
// ---------------------------------------------------------------------------
__global__ __launch_bounds__(256) void crf_kernel(const float* __restrict__ gram,
                                                  const float* __restrict__ logits,
                                                  const float* __restrict__ Wm,
                                                  float* __restrict__ out) {
    __shared__ float pp[NN][NN + 1];
    __shared__ float E[NN];
    __shared__ float nrm[NN];
    __shared__ float part[4 * NN];

    const int b  = blockIdx.x;
    const int tid = threadIdx.x;
    const int i  = tid & 63;
    const int jq = tid >> 6;
    const float* g = gram + b * NN * NN;

    if (jq == 0) nrm[i] = sqrtf(g[i * NN + i]);
    E[i] = 0.0f;
    __syncthreads();

    const float ni = nrm[i];
    for (int jj = 0; jj < 16; ++jj) {
        int j = jq * 16 + jj;
        float wsym = 0.5f * (Wm[i * NN + j] + Wm[j * NN + i]);
        pp[i][j] = g[i * NN + j] / (ni * nrm[j] + 1e-6f) * wsym;
    }
    const float li = logits[b * NN + i];
    __syncthreads();

    for (int it = 0; it < 10; ++it) {
        float acc = 0.0f;
        for (int jj = 0; jj < 16; ++jj) {
            int j = jq * 16 + jj;
            float t = li + E[j];
            float s = 1.0f / (1.0f + expf(-t));
            acc = fmaf(2.0f * s - 1.0f, pp[i][j], acc);
        }
        part[jq * NN + i] = acc;
        __syncthreads();
        if (jq == 0)
            E[i] = part[i] + part[NN + i] + part[2 * NN + i] + part[3 * NN + i];
        __syncthreads();
    }

    // out[b][j] = logits[b][j] + mean_i(E[i])
    if (tid < 64) {
        float s = E[tid];
        for (int off = 32; off > 0; off >>= 1) s += __shfl_down(s, off);
        float meanE = __shfl(s, 0) * (1.0f / 64.0f);
        out[b * NN + tid] = logits[b * NN + tid] + meanE;
    }
}

extern "C" void kernel_launch(void* const* d_in, const int* in_sizes, int n_in,
                              void* d_out, int out_size, void* d_ws, size_t ws_size,
                              hipStream_t stream) {
    const float* a      = (const float*)d_in[0];  // [8,64,64,32,32]
    const float* logits = (const float*)d_in[1];  // [8,64]
    const float* Wm     = (const float*)d_in[2];  // [1,64,64]
    float* out  = (float*)d_out;                  // [8,64]
    float* gram = (float*)d_ws;                   // [8,64,64] fp32 accumulators

    hipMemsetAsync(d_ws, 0, (size_t)BATCH * NN * NN * sizeof(float), stream);
    gram_kernel<<<BATCH * CH, 256, 0, stream>>>(a, gram);
    crf_kernel<<<BATCH, 64 * 4, 0, stream>>>(gram, logits, Wm, out);
}

// Round 2
// 261.157 us; speedup vs baseline: 1.0891x; 1.0891x over previous
//
#include <hip/hip_runtime.h>
#include <math.h>

// Problem constants
#define BATCH 8
#define NN 64
#define DD 65536          // 64*32*32 feature length (contiguous per [b,n])
#define CH 128            // K-chunks per batch -> grid = 8*128 = 1024 blocks
#define KC (DD / CH)      // 512 K per block
#define BK 64             // K per LDS tile
#define NIT (KC / BK)     // 8 tile iterations per block
#define LSTRIDE 72        // LDS row stride in halfwords (64 + 8 pad)

typedef float  floatx4 __attribute__((ext_vector_type(4)));
typedef __bf16 bf16x8  __attribute__((ext_vector_type(8)));

// fp32 -> bf16 round-to-nearest-even (bit trick; inputs are finite randoms)
static __device__ __forceinline__ unsigned short f2bf(float f) {
    union { float f; unsigned u; } x;
    x.f = f;
    unsigned r = x.u + 0x7FFFu + ((x.u >> 16) & 1u);
    return (unsigned short)(r >> 16);
}

// ---------------------------------------------------------------------------
// Stage 1: per-chunk partial Gram matrices, NON-atomic, into part[bid][64*64].
// 1024 blocks x 256 threads (4 waves). Double-buffered LDS, ONE barrier per
// K-tile: wave at iter k+2 can only reach its store of lds[k%2] after the
// whole block passed the barrier of iter k+1, and the compiler's
// s_waitcnt lgkmcnt(0) before s_barrier guarantees iter-k ds_reads drained.
// ---------------------------------------------------------------------------
__global__ __launch_bounds__(256) void gram_partial_kernel(const float* __restrict__ a,
                                                           float* __restrict__ part) {
    __shared__ __align__(16) unsigned short lds[2][NN * LSTRIDE];

    const int bid = blockIdx.x;
    const int b = bid >> 7;           // / CH
    const int c = bid & (CH - 1);
    const float* base = a + (size_t)b * NN * DD + (size_t)c * KC;

    const int tid  = threadIdx.x;
    const int w    = tid >> 6;        // wave id 0..3 -> output row band
    const int lane = tid & 63;
    const int m    = lane & 15;
    const int q    = lane >> 4;

    // Per-thread staging coords: flat float4 index F = sub*256 + tid
    int rowv[4], kqv[4];
    for (int sub = 0; sub < 4; ++sub) {
        int F = sub * 256 + tid;
        rowv[sub] = F >> 4;
        kqv[sub]  = F & 15;
    }

    floatx4 acc[4];
    for (int t = 0; t < 4; ++t) acc[t] = (floatx4)0.0f;

    float4 regs[4];
    for (int sub = 0; sub < 4; ++sub)
        regs[sub] = *(const float4*)(base + (size_t)rowv[sub] * DD + kqv[sub] * 4);

    for (int kt = 0; kt < NIT; ++kt) {
        unsigned short* buf = lds[kt & 1];

        // stage current regs into LDS as bf16 (waits on the in-flight loads)
        for (int sub = 0; sub < 4; ++sub) {
            ushort4 h;
            h.x = f2bf(regs[sub].x);
            h.y = f2bf(regs[sub].y);
            h.z = f2bf(regs[sub].z);
            h.w = f2bf(regs[sub].w);
            *reinterpret_cast<ushort4*>(&buf[rowv[sub] * LSTRIDE + kqv[sub] * 4]) = h;
        }
        __syncthreads();

        // issue next tile's loads immediately after the barrier
        if (kt + 1 < NIT) {
            const float* nb = base + (size_t)(kt + 1) * BK;
            for (int sub = 0; sub < 4; ++sub)
                regs[sub] = *(const float4*)(nb + (size_t)rowv[sub] * DD + kqv[sub] * 4);
        }

        // MFMA over this BK=64 tile: two K=32 steps; A-frag == B-frag (Gram)
        for (int s = 0; s < 2; ++s) {
            int kb = s * 32 + q * 8;
            bf16x8 fr[4];
            for (int t = 0; t < 4; ++t)
                fr[t] = *reinterpret_cast<const bf16x8*>(&buf[(16 * t + m) * LSTRIDE + kb]);
            bf16x8 A = fr[w];
            for (int t = 0; t < 4; ++t)
                acc[t] = __builtin_amdgcn_mfma_f32_16x16x32_bf16(A, fr[t], acc[t], 0, 0, 0);
        }
        // no second barrier: next iter writes the OTHER buffer
    }

    // C/D layout: C[row=(lane>>4)*4+r][col=lane&15] (swap-safe: G symmetric)
    float* pg = part + (size_t)bid * (NN * NN);
    for (int t = 0; t < 4; ++t)
        for (int r = 0; r < 4; ++r) {
            int i = 16 * w + q * 4 + r;
            int j = 16 * t + m;
            pg[i * NN + j] = acc[t][r];
        }
}

// ---------------------------------------------------------------------------
// Stage 1b: reduce CH partials per batch -> gram[8][64*64].
// 256 blocks x 128 threads; thread owns one output element, sums CH values
// strided 16 KB apart (coalesced across the wave at every c).
// ---------------------------------------------------------------------------
__global__ __launch_bounds__(128) void gram_reduce_kernel(const float* __restrict__ part,
                                                          float* __restrict__ gram) {
    const int gid = blockIdx.x * 128 + threadIdx.x;   // 0 .. 8*4096-1
    const int b   = gid >> 12;
    const int idx = gid & 4095;
    const float* p = part + (size_t)b * CH * (NN * NN) + idx;

    float s0 = 0.f, s1 = 0.f, s2 = 0.f, s3 = 0.f;
    #pragma unroll
    for (int c = 0; c < CH; c += 4) {
        s0 += p[(size_t)(c + 0) * (NN * NN)];
        s1 += p[(size_t)(c + 1) * (NN * NN)];
        s2 += p[(size_t)(c + 2) * (NN * NN)];
        s3 += p[(size_t)(c + 3) * (NN * NN)];
    }
    gram[gid] = (s0 + s1) + (s2 + s3);
}

// ---------------------------------------------------------------------------
// Stage 2: per-batch CRF iterations. 8 blocks x 256 threads.
// thread = (i = tid&63, jq = tid>>6): each thread owns a 16-wide j-chunk of row i.
// ---------------------------------------------------------------------------
__global__ __launch_bounds__(256) void crf_kernel(const float* __restrict__ gram,
                                                  const float* __restrict__ logits,
                                                  const float* __restrict__ Wm,
                                                  float* __restrict__ out) {
    __shared__ float pp[NN][NN + 1];
    __shared__ float E[NN];
    __shared__ float nrm[NN];
    __shared__ float part[4 * NN];

    const int b  = blockIdx.x;
    const int tid = threadIdx.x;
    const int i  = tid & 63;
    const int jq = tid >> 6;
    const float* g = gram + b * NN * NN;

    if (jq == 0) nrm[i] = sqrtf(g[i * NN + i]);
    E[i] = 0.0f;
    __syncthreads();

    const float ni = nrm[i];
    for (int jj = 0; jj < 16; ++jj) {
        int j = jq * 16 + jj;
        float wsym = 0.5f * (Wm[i * NN + j] + Wm[j * NN + i]);
        pp[i][j] = g[i * NN + j] / (ni * nrm[j] + 1e-6f) * wsym;
    }
    const float li = logits[b * NN + i];
    __syncthreads();

    for (int it = 0; it < 10; ++it) {
        float acc = 0.0f;
        for (int jj = 0; jj < 16; ++jj) {
            int j = jq * 16 + jj;
            float t = li + E[j];
            float s = 1.0f / (1.0f + expf(-t));
            acc = fmaf(2.0f * s - 1.0f, pp[i][j], acc);
        }
        part[jq * NN + i] = acc;
        __syncthreads();
        if (jq == 0)
            E[i] = part[i] + part[NN + i] + part[2 * NN + i] + part[3 * NN + i];
        __syncthreads();
    }

    // out[b][j] = logits[b][j] + mean_i(E[i])
    if (tid < 64) {
        float s = E[tid];
        for (int off = 32; off > 0; off >>= 1) s += __shfl_down(s, off);
        float meanE = __shfl(s, 0) * (1.0f / 64.0f);
        out[b * NN + tid] = logits[b * NN + tid] + meanE;
    }
}

extern "C" void kernel_launch(void* const* d_in, const int* in_sizes, int n_in,
                              void* d_out, int out_size, void* d_ws, size_t ws_size,
                              hipStream_t stream) {
    const float* a      = (const float*)d_in[0];  // [8,64,64,32,32]
    const float* logits = (const float*)d_in[1];  // [8,64]
    const float* Wm     = (const float*)d_in[2];  // [1,64,64]
    float* out  = (float*)d_out;                  // [8,64]

    float* part = (float*)d_ws;                           // [1024][4096] fp32
    float* gram = part + (size_t)BATCH * CH * NN * NN;    // [8][4096]

    gram_partial_kernel<<<BATCH * CH, 256, 0, stream>>>(a, part);
    gram_reduce_kernel<<<(BATCH * NN * NN) / 128, 128, 0, stream>>>(part, gram);
    crf_kernel<<<BATCH, 256, 0, stream>>>(gram, logits, Wm, out);
}

// Round 3
// 236.440 us; speedup vs baseline: 1.2030x; 1.1045x over previous
//
#include <hip/hip_runtime.h>
#include <math.h>

// Problem constants
#define BATCH 8
#define NN 64
#define DD 65536          // 64*32*32 feature length (contiguous per [b,n])
#define CH 128            // K-chunks per batch -> grid = 8*128 = 1024 blocks
#define KC (DD / CH)      // 512 K per block
#define KSTEPS (KC / 32)  // 16 MFMA K-steps per block

typedef float  floatx4 __attribute__((ext_vector_type(4)));
typedef __bf16 bf16x8  __attribute__((ext_vector_type(8)));

// Pack 8 fp32 -> 8 bf16 via v_perm_b32 (truncation). Bias is a uniform
// relative shrink; cosine similarity is scale-invariant, so it cancels to
// first order. 1 VALU op per 2 elements vs 3/elem for the RNE bit trick.
static __device__ __forceinline__ bf16x8 cvt8(float4 lo, float4 hi) {
    const unsigned sel = 0x07060302u;  // bytes [f0.b2,f0.b3,f1.b2,f1.b3]
    union { unsigned u[4]; bf16x8 v; } r;
    r.u[0] = __builtin_amdgcn_perm(__float_as_uint(lo.y), __float_as_uint(lo.x), sel);
    r.u[1] = __builtin_amdgcn_perm(__float_as_uint(lo.w), __float_as_uint(lo.z), sel);
    r.u[2] = __builtin_amdgcn_perm(__float_as_uint(hi.y), __float_as_uint(hi.x), sel);
    r.u[3] = __builtin_amdgcn_perm(__float_as_uint(hi.w), __float_as_uint(hi.z), sel);
    return r.v;
}

// ---------------------------------------------------------------------------
// Stage 1: per-chunk partial Gram matrices. NO LDS, NO BARRIERS.
// 1024 blocks x 4 waves. Wave w computes output row-band w (tiles (w, w^i)).
// Fragments loaded straight from global: lane(m,q) of band t holds
// row (16t+m), k = q*8..q*8+7 — the layout HW-validated in R1/R2.
// A-frag == B-frag of band w == frag i=0 (XOR band ordering), so no selects.
// All K-step offsets are compile-time immediates; compiler pipelines loads
// across the fully-unrolled 16 steps with fine-grained vmcnt.
// ---------------------------------------------------------------------------
__global__ __launch_bounds__(256, 4) void gram_partial_kernel(const float* __restrict__ a,
                                                              float* __restrict__ part) {
    const int bid = blockIdx.x;
    const int b = bid >> 7;           // / CH
    const int c = bid & (CH - 1);

    const int tid  = threadIdx.x;
    const int w    = tid >> 6;        // wave id 0..3 -> output row band
    const int lane = tid & 63;
    const int m    = lane & 15;
    const int q    = lane >> 4;

    const float* base = a + (size_t)b * NN * DD + (size_t)c * KC
                          + (size_t)m * DD + q * 8;
    const float* p[4];
    #pragma unroll
    for (int i = 0; i < 4; ++i)
        p[i] = base + (size_t)((w ^ i) * 16) * DD;   // band w^i; i=0 is own band

    floatx4 acc[4];
    #pragma unroll
    for (int i = 0; i < 4; ++i) acc[i] = (floatx4)0.0f;

    #pragma unroll
    for (int s = 0; s < KSTEPS; ++s) {
        const int o = s * 32;         // byte offset s*128 (+16) — fits 13-bit imm
        float4 l0 = *(const float4*)(p[0] + o);
        float4 h0 = *(const float4*)(p[0] + o + 4);
        float4 l1 = *(const float4*)(p[1] + o);
        float4 h1 = *(const float4*)(p[1] + o + 4);
        float4 l2 = *(const float4*)(p[2] + o);
        float4 h2 = *(const float4*)(p[2] + o + 4);
        float4 l3 = *(const float4*)(p[3] + o);
        float4 h3 = *(const float4*)(p[3] + o + 4);

        bf16x8 f0 = cvt8(l0, h0);     // own band = A operand
        bf16x8 f1 = cvt8(l1, h1);
        bf16x8 f2 = cvt8(l2, h2);
        bf16x8 f3 = cvt8(l3, h3);

        acc[0] = __builtin_amdgcn_mfma_f32_16x16x32_bf16(f0, f0, acc[0], 0, 0, 0);
        acc[1] = __builtin_amdgcn_mfma_f32_16x16x32_bf16(f0, f1, acc[1], 0, 0, 0);
        acc[2] = __builtin_amdgcn_mfma_f32_16x16x32_bf16(f0, f2, acc[2], 0, 0, 0);
        acc[3] = __builtin_amdgcn_mfma_f32_16x16x32_bf16(f0, f3, acc[3], 0, 0, 0);
    }

    // Tile (w, t=w^i): C/D layout row=(q*4+r), col=m within tile.
    // part[bid] holds 16 tiles of 256 floats at slot (w*4 + t).
    float* pg = part + (size_t)bid * (NN * NN);
    #pragma unroll
    for (int i = 0; i < 4; ++i) {
        const int t = w ^ i;
        float* tp = pg + (w * 4 + t) * 256 + m;
        #pragma unroll
        for (int r = 0; r < 4; ++r)
            tp[(q * 4 + r) * 16] = acc[i][r];
    }
}

// ---------------------------------------------------------------------------
// Stage 1b: reduce CH partials per batch -> gram[8][64*64] (row-major i*64+j).
// ---------------------------------------------------------------------------
__global__ __launch_bounds__(128) void gram_reduce_kernel(const float* __restrict__ part,
                                                          float* __restrict__ gram) {
    const int gid = blockIdx.x * 128 + threadIdx.x;   // 0 .. 8*4096-1
    const int b   = gid >> 12;
    const int idx = gid & 4095;
    const int i   = idx >> 6;
    const int j   = idx & 63;
    const int off = ((i >> 4) * 4 + (j >> 4)) * 256 + (i & 15) * 16 + (j & 15);
    const float* p = part + (size_t)b * CH * (NN * NN) + off;

    float s0 = 0.f, s1 = 0.f, s2 = 0.f, s3 = 0.f;
    #pragma unroll
    for (int c = 0; c < CH; c += 4) {
        s0 += p[(size_t)(c + 0) * (NN * NN)];
        s1 += p[(size_t)(c + 1) * (NN * NN)];
        s2 += p[(size_t)(c + 2) * (NN * NN)];
        s3 += p[(size_t)(c + 3) * (NN * NN)];
    }
    gram[gid] = (s0 + s1) + (s2 + s3);
}

// ---------------------------------------------------------------------------
// Stage 2: per-batch CRF iterations. 8 blocks x 256 threads.
// thread = (i = tid&63, jq = tid>>6): each thread owns a 16-wide j-chunk of row i.
// ---------------------------------------------------------------------------
__global__ __launch_bounds__(256) void crf_kernel(const float* __restrict__ gram,
                                                  const float* __restrict__ logits,
                                                  const float* __restrict__ Wm,
                                                  float* __restrict__ out) {
    __shared__ float pp[NN][NN + 1];
    __shared__ float E[NN];
    __shared__ float nrm[NN];
    __shared__ float part[4 * NN];

    const int b  = blockIdx.x;
    const int tid = threadIdx.x;
    const int i  = tid & 63;
    const int jq = tid >> 6;
    const float* g = gram + b * NN * NN;

    if (jq == 0) nrm[i] = sqrtf(g[i * NN + i]);
    E[i] = 0.0f;
    __syncthreads();

    const float ni = nrm[i];
    for (int jj = 0; jj < 16; ++jj) {
        int j = jq * 16 + jj;
        float wsym = 0.5f * (Wm[i * NN + j] + Wm[j * NN + i]);
        pp[i][j] = g[i * NN + j] / (ni * nrm[j] + 1e-6f) * wsym;
    }
    const float li = logits[b * NN + i];
    __syncthreads();

    for (int it = 0; it < 10; ++it) {
        float acc = 0.0f;
        for (int jj = 0; jj < 16; ++jj) {
            int j = jq * 16 + jj;
            float t = li + E[j];
            float s = 1.0f / (1.0f + expf(-t));
            acc = fmaf(2.0f * s - 1.0f, pp[i][j], acc);
        }
        part[jq * NN + i] = acc;
        __syncthreads();
        if (jq == 0)
            E[i] = part[i] + part[NN + i] + part[2 * NN + i] + part[3 * NN + i];
        __syncthreads();
    }

    // out[b][j] = logits[b][j] + mean_i(E[i])
    if (tid < 64) {
        float s = E[tid];
        for (int off = 32; off > 0; off >>= 1) s += __shfl_down(s, off);
        float meanE = __shfl(s, 0) * (1.0f / 64.0f);
        out[b * NN + tid] = logits[b * NN + tid] + meanE;
    }
}

extern "C" void kernel_launch(void* const* d_in, const int* in_sizes, int n_in,
                              void* d_out, int out_size, void* d_ws, size_t ws_size,
                              hipStream_t stream) {
    const float* a      = (const float*)d_in[0];  // [8,64,64,32,32]
    const float* logits = (const float*)d_in[1];  // [8,64]
    const float* Wm     = (const float*)d_in[2];  // [1,64,64]
    float* out  = (float*)d_out;                  // [8,64]

    float* part = (float*)d_ws;                           // [1024][4096] fp32
    float* gram = part + (size_t)BATCH * CH * NN * NN;    // [8][4096]

    gram_partial_kernel<<<BATCH * CH, 256, 0, stream>>>(a, part);
    gram_reduce_kernel<<<(BATCH * NN * NN) / 128, 128, 0, stream>>>(part, gram);
    crf_kernel<<<BATCH, 256, 0, stream>>>(gram, logits, Wm, out);
}